// Round 12
// baseline (103.205 us; speedup 1.0000x reference)
//
#include <hip/hip_runtime.h>

#define SEQ   512
#define BATCH 256

// Lane broadcast via v_readlane (immediate index after unroll, or SGPR).
__device__ __forceinline__ float bcast_f(float v, int l) {
    return __int_as_float(__builtin_amdgcn_readlane(__float_as_int(v), l));
}
// gfx950: v_log_f32 is log2, v_exp_f32 is exp2.
__device__ __forceinline__ float flog2(float x) { return __builtin_amdgcn_logf(x); }
__device__ __forceinline__ float fexp2(float x) { return __builtin_amdgcn_exp2f(x); }

// One block (256 threads = 4 waves, 1/SIMD) per batch column. Flag pipeline,
// no barriers after init. Wave w owns diag blocks {w, w+4} (spine round-robin
// d0..d7 over waves). Serial chain uses a REPLICATED carry: em lives in all
// lanes; per step the cross-lane base extraction (readlane) is issued a full
// mul+exp ahead of its use, so readlane/SGPR wait-states hide under the trans
// latency. Chain terms are bitwise equal to the vector-sweep terms at the
// corresponding lane, so em stays exactly consistent with acc.
// Maskless sweep: at step j lanes i<=j add exactly 1.0 (L=0); 63 sweep steps
// -> subtract (63-lane) at publish. Row bases extracted pre-contamination.
__global__ void __launch_bounds__(256, 1)
act_r_kernel(const float* __restrict__ sp, const float* __restrict__ w,
             float* __restrict__ out) {
    __shared__ float x_lds[SEQ];
    __shared__ float p_lds[SEQ];     // published p_i = -(a + c*expm_i)
    __shared__ float part6[64];      // w0's S(0->6) assist
    __shared__ float part7[64];      // w0's S(0->7)+S(1->7) assist
    __shared__ int   flag_lds[10];   // 0..7 block flags; 8=part7; 9=part6

    const int b    = blockIdx.x;
    const int tid  = threadIdx.x;
    const int wid  = tid >> 6;
    const int lane = tid & 63;
    volatile int* flag = flag_lds;

    const float a = w[0], c = w[1], s = w[2], tau = w[3], h = w[4];
    const float scale = 86400.0f * h;
    const float na = -a, nc = -c;
    const float k1 = tau / s * 1.4426950408889634f;
    const float k2 = 1.0f / s;

    if (tid < 10) flag_lds[tid] = 0;
    x_lds[tid]       = sp[tid * BATCH + b] * scale;
    x_lds[tid + 256] = sp[(tid + 256) * BATCH + b] * scale;
    __syncthreads();   // the only barrier

    // ---- deep sweep: col block K (published) -> row acc (rows = lanes of xr)
    auto sweep = [&](int K, float xr, float& acc) {
        while (flag[K] == 0) {}
        __asm__ __volatile__("" ::: "memory");
        const float pv = p_lds[(K << 6) | lane];
        const float xc = x_lds[(K << 6) | lane];
        float s0 = 0.0f, s1 = 0.0f;
#pragma unroll
        for (int j = 0; j < 64; j += 2) {
            s0 += fexp2(bcast_f(pv, j)     * flog2(fmaxf(xr - bcast_f(xc, j),     1.0f)));
            s1 += fexp2(bcast_f(pv, j + 1) * flog2(fmaxf(xr - bcast_f(xc, j + 1), 1.0f)));
        }
        acc += s0 + s1;
    };

    // ---- diag prologue: all logs + subdiag uniforms (no flag dependency)
    auto prol = [&](int K, float xd, float (&Ld)[64], float (&Lp)[64],
                    float (&Ls)[63]) {
#pragma unroll
        for (int j = 0; j < 64; ++j)
            Ld[j] = flog2(fmaxf(xd - bcast_f(xd, j), 1.0f));
        if (K > 0) {
            const float xc = x_lds[((K - 1) << 6) | lane];
#pragma unroll
            for (int j = 0; j < 64; ++j)
                Lp[j] = flog2(fmaxf(xd - bcast_f(xc, j), 1.0f));
        }
#pragma unroll
        for (int j = 0; j < 63; ++j)
            Ls[j] = bcast_f(Ld[j], j + 1);
    };

    // ---- diag main: optional LDS-partial merge, panel, replicated chain
    auto diag_main = [&](int K, float& acc, float (&Ld)[64], float (&Lp)[64],
                         float (&Ls)[63], int mflag, const float* mbuf) {
        if (mflag >= 0) {
            while (flag[mflag] == 0) {}
            __asm__ __volatile__("" ::: "memory");
            acc += mbuf[lane];
        }
        if (K > 0) {
            while (flag[K - 1] == 0) {}
            __asm__ __volatile__("" ::: "memory");
            const float pv = p_lds[((K - 1) << 6) | lane];
            float s0 = 0.0f, s1 = 0.0f;
#pragma unroll
            for (int j = 0; j < 64; j += 2) {
                s0 += fexp2(bcast_f(pv, j)     * Lp[j]);
                s1 += fexp2(bcast_f(pv, j + 1) * Lp[j + 1]);
            }
            acc += s0 + s1;
        }
        // replicated-carry chain, 63 sweep steps (step 63 would add all-1.0)
        float em = bcast_f(acc, 0);
#pragma unroll
        for (int j = 0; j < 63; ++j) {
            const float sB  = bcast_f(acc, j + 1);   // pre-update base, off-chain
            const float p   = fmaf(nc, em, na);      // chain
            const float tch = fexp2(p * Ls[j]);      // chain (uniform Ls)
            const float tv  = fexp2(p * Ld[j]);      // vector sweep
            acc += tv;
            em = sB + tch;                           // = acc[j+1] bitwise
        }
        const float clean = acc - (float)(63 - lane);
        p_lds[(K << 6) | lane] = -fmaf(c, clean, a);
        __asm__ __volatile__("s_waitcnt lgkmcnt(0)" ::: "memory");
        flag[K] = 1;                                 // release
        const int i = (K << 6) | lane;               // epilogue (off-spine)
        if (i >= 1) {
            const float q = k1 - k2 * flog2(clean);
            out[(i - 1) * BATCH + b] = 1.0f / (1.0f + fexp2(q));
        }
    };

    float Ld[64], Lp[64], Ls[63];

    if (wid == 0) {
        const float x0 = x_lds[lane], x4 = x_lds[(4 << 6) | lane];
        const float x6 = x_lds[(6 << 6) | lane], x7 = x_lds[(7 << 6) | lane];
        float acc0 = 0.0f, acc4 = 0.0f, acc6p = 0.0f, acc7p = 0.0f;
        prol(0, x0, Ld, Lp, Ls);
        diag_main(0, acc0, Ld, Lp, Ls, -1, nullptr);
        prol(4, x4, Ld, Lp, Ls);
        sweep(0, x4, acc4); sweep(1, x4, acc4); sweep(2, x4, acc4);
        diag_main(4, acc4, Ld, Lp, Ls, -1, nullptr);
        sweep(0, x6, acc6p);
        part6[lane] = acc6p;
        __asm__ __volatile__("s_waitcnt lgkmcnt(0)" ::: "memory");
        flag[9] = 1;
        sweep(0, x7, acc7p); sweep(1, x7, acc7p);
        part7[lane] = acc7p;
        __asm__ __volatile__("s_waitcnt lgkmcnt(0)" ::: "memory");
        flag[8] = 1;
    } else if (wid == 1) {
        const float x1 = x_lds[(1 << 6) | lane], x5 = x_lds[(5 << 6) | lane];
        float acc1 = 0.0f, acc5 = 0.0f;
        prol(1, x1, Ld, Lp, Ls);
        diag_main(1, acc1, Ld, Lp, Ls, -1, nullptr);
        prol(5, x5, Ld, Lp, Ls);
        sweep(0, x5, acc5); sweep(1, x5, acc5); sweep(2, x5, acc5); sweep(3, x5, acc5);
        diag_main(5, acc5, Ld, Lp, Ls, -1, nullptr);
    } else if (wid == 2) {
        const float x2 = x_lds[(2 << 6) | lane], x6 = x_lds[(6 << 6) | lane];
        float acc2 = 0.0f, acc6 = 0.0f;
        prol(2, x2, Ld, Lp, Ls);
        sweep(0, x2, acc2);
        diag_main(2, acc2, Ld, Lp, Ls, -1, nullptr);
        prol(6, x6, Ld, Lp, Ls);
        sweep(1, x6, acc6); sweep(2, x6, acc6); sweep(3, x6, acc6); sweep(4, x6, acc6);
        diag_main(6, acc6, Ld, Lp, Ls, 9, part6);
    } else {
        const float x3 = x_lds[(3 << 6) | lane], x7 = x_lds[(7 << 6) | lane];
        float acc3 = 0.0f, acc7 = 0.0f;
        prol(3, x3, Ld, Lp, Ls);
        sweep(0, x3, acc3); sweep(1, x3, acc3);
        diag_main(3, acc3, Ld, Lp, Ls, -1, nullptr);
        prol(7, x7, Ld, Lp, Ls);
        sweep(2, x7, acc7); sweep(3, x7, acc7); sweep(4, x7, acc7); sweep(5, x7, acc7);
        diag_main(7, acc7, Ld, Lp, Ls, 8, part7);
    }
}

extern "C" void kernel_launch(void* const* d_in, const int* in_sizes, int n_in,
                              void* d_out, int out_size, void* d_ws, size_t ws_size,
                              hipStream_t stream) {
    const float* sp = (const float*)d_in[0];  // [512, 256, 1] f32
    const float* w  = (const float*)d_in[1];  // [5] f32
    float* out = (float*)d_out;               // [511, 256, 1] f32
    (void)in_sizes; (void)n_in; (void)out_size; (void)d_ws; (void)ws_size;

    act_r_kernel<<<dim3(BATCH), dim3(256), 0, stream>>>(sp, w, out);
}